// Round 3
// baseline (542.215 us; speedup 1.0000x reference)
//
#include <hip/hip_runtime.h>
#include <cstdint>
#include <cstddef>

#define DI __device__ __forceinline__

typedef __attribute__((ext_vector_type(8))) short short8;
typedef __attribute__((ext_vector_type(4))) float floatx4;

static constexpr int BATCH = 16384;
static constexpr int H = 1024;

DI unsigned short f32_to_bf16_bits(float x) {
  union { float f; unsigned int u; } c; c.f = x;
  unsigned int r = c.u + 0x7fffu + ((c.u >> 16) & 1u);
  return (unsigned short)(r >> 16);
}

DI float bf16_bits_to_f32(unsigned short b) {
  union { unsigned int u; float f; } c; c.u = ((unsigned int)b) << 16;
  return c.f;
}

// ---------------- K0a: fp32 -> bf16 cast (prev), vectorized ----------------
__global__ __launch_bounds__(256) void cast_bf16_kernel(const float* __restrict__ in,
                                                        unsigned short* __restrict__ out) {
  const int i = (blockIdx.x * 256 + threadIdx.x) * 4;
  const float4 v = *reinterpret_cast<const float4*>(in + i);
  ushort4 o;
  o.x = f32_to_bf16_bits(v.x);
  o.y = f32_to_bf16_bits(v.y);
  o.z = f32_to_bf16_bits(v.z);
  o.w = f32_to_bf16_bits(v.w);
  *reinterpret_cast<ushort4*>(out + i) = o;
}

// ------------- K0b/c: transpose + cast: out[n][k] = in[k][col0 + n] --------
__global__ __launch_bounds__(256) void transpose_cast_kernel(const float* __restrict__ in,
                                                             unsigned short* __restrict__ out,
                                                             int src_stride, int src_col0) {
  __shared__ float tile[32][33];
  const int bx = blockIdx.x * 32;  // k (input row)
  const int by = blockIdx.y * 32;  // n (input col)
  const int tx = threadIdx.x;
  const int ty = threadIdx.y;
#pragma unroll
  for (int i = 0; i < 32; i += 8)
    tile[ty + i][tx] = in[(size_t)(bx + ty + i) * src_stride + src_col0 + by + tx];
  __syncthreads();
#pragma unroll
  for (int i = 0; i < 32; i += 8)
    out[(size_t)(by + ty + i) * H + bx + tx] = f32_to_bf16_bits(tile[tx][ty + i]);
}

// ------------- panel GEMM: C[M x 64-col-slab] = A(MxK) @ Bt(NxK)^T ----------
// Weight panel (64 cols x 512 K-half, bf16, XOR-swizzled) lives in LDS; batch
// rows stream through with NO barriers in the k-loop. A-frags come straight
// from global (L2-resident via the p->XCD swizzle). grid: bx = n*32 + p so
// XCD = bx%8 = p%8 -> the 16 blocks sharing an A row-strip share one XCD L2.
// 512 thr (8 waves), 64 KB LDS -> 2 blocks/CU, 512 blocks = all co-resident.
template <int EPI>
__global__ __launch_bounds__(512, 4) void gemm_panel(const unsigned short* __restrict__ A,
                                                     const unsigned short* __restrict__ Bt,
                                                     const float* __restrict__ inp,
                                                     const unsigned short* __restrict__ prevb,
                                                     const float* __restrict__ mask,
                                                     unsigned short* __restrict__ Xout,
                                                     float* __restrict__ Out) {
  __shared__ __align__(16) unsigned short panel[64 * 512];  // 64 KB

  const int tid = threadIdx.x;
  const int lane = tid & 63;
  const int wave = tid >> 6;      // 0..7
  const int q = lane >> 4;        // 0..3
  const int l16 = lane & 15;
  const int p = blockIdx.x & 31;  // M-strip 0..31 (rows p*512..)
  const int n = blockIdx.x >> 5;  // N-slab 0..15 (cols n*64..)
  const int row0 = p * 512 + wave * 64;
  const int col0 = n * 64;

  floatx4 acc[4][4] = {};  // [row-chunk][n-tile]

  for (int kh = 0; kh < 2; ++kh) {
    __syncthreads();  // panel reuse guard (kh=1: prior reads must finish)
    // stage 64x512 bf16 panel: 4096 16B-chunks / 512 thr = 8 each.
    // phys chunk within row: low 3 bits XOR row (2-way read conflicts = free)
#pragma unroll
    for (int i = 0; i < 8; ++i) {
      const int g = i * 512 + tid;
      const int r = g >> 6;       // panel row 0..63
      const int c = g & 63;       // chunk in row
      const short8 v = *(const short8*)&Bt[(size_t)(col0 + r) * H + kh * 512 + c * 8];
      const int pc = (c & ~7) | ((c & 7) ^ (r & 7));
      *(short8*)&panel[r * 512 + pc * 8] = v;
    }
    __syncthreads();

    // barrier-free K-stream: 16 k-steps of 32
    for (int ks = 0; ks < 16; ++ks) {
      short8 bf[4];
#pragma unroll
      for (int nt = 0; nt < 4; ++nt) {
        const int r = nt * 16 + l16;
        const int c = ks * 4 + q;
        const int pc = (c & ~7) | ((c & 7) ^ (r & 7));
        bf[nt] = *(const short8*)&panel[r * 512 + pc * 8];
      }
#pragma unroll
      for (int ch = 0; ch < 4; ++ch) {
        const int grow = row0 + ch * 16 + l16;
        const short8 af = *(const short8*)&A[(size_t)grow * H + kh * 512 + ks * 32 + q * 8];
#pragma unroll
        for (int nt = 0; nt < 4; ++nt)
          acc[ch][nt] = __builtin_amdgcn_mfma_f32_16x16x32_bf16(af, bf[nt], acc[ch][nt], 0, 0, 0);
      }
    }
  }

  // epilogue. C/D map: col = lane&15, row = quad*4 + reg (verified m89/m91)
#pragma unroll
  for (int ch = 0; ch < 4; ++ch) {
    const int gr0 = row0 + ch * 16 + q * 4;
#pragma unroll
    for (int nt = 0; nt < 4; ++nt) {
      const int gcol = col0 + nt * 16 + l16;
#pragma unroll
      for (int rg = 0; rg < 4; ++rg) {
        const int gr = gr0 + rg;
        const float v = acc[ch][nt][rg];
        if (EPI == 0) {
          // reset = sigmoid(G + gate_r); X = state_inp * reset
          const float z = v + inp[(size_t)gr * (3 * H) + 2 * H + gcol];
          const float rst = 1.0f / (1.0f + __expf(-z));
          const float x = inp[(size_t)gr * (3 * H) + gcol] * rst;
          Xout[(size_t)gr * H + gcol] = f32_to_bf16_bits(x);
        } else {
          // out = mask*(tanh(P + s) + 1) + prev   [update-gate cancels exactly]
          const float s = inp[(size_t)gr * (3 * H) + gcol];
          const float a = v + s;
          const float ns = 1.0f - 2.0f / (__expf(2.0f * a) + 1.0f);  // tanh
          const float m = mask[gr];
          const float pv = bf16_bits_to_f32(prevb[(size_t)gr * H + gcol]);
          Out[(size_t)gr * H + gcol] = m * (ns + 1.0f) + pv;
        }
      }
    }
  }
}

extern "C" void kernel_launch(void* const* d_in, const int* in_sizes, int n_in,
                              void* d_out, int out_size, void* d_ws, size_t ws_size,
                              hipStream_t stream) {
  const float* inp = (const float*)d_in[0];    // (B, 3H)
  const float* prev = (const float*)d_in[1];   // (B, H)
  const float* mask = (const float*)d_in[2];   // (B,)
  const float* Wur = (const float*)d_in[3];    // (H, 2H)
  const float* U = (const float*)d_in[4];      // (H, H)
  float* out = (float*)d_out;

  // workspace layout
  char* ws = (char*)d_ws;
  unsigned short* prevb = (unsigned short*)ws;                          // B*H bf16
  unsigned short* Xb = (unsigned short*)(ws + (size_t)BATCH * H * 2);   // B*H bf16
  unsigned short* WrT = (unsigned short*)(ws + (size_t)BATCH * H * 4);  // H*H bf16
  unsigned short* UT = WrT + (size_t)H * H;                             // H*H bf16

  cast_bf16_kernel<<<(BATCH * H) / (256 * 4), 256, 0, stream>>>(prev, prevb);
  transpose_cast_kernel<<<dim3(H / 32, H / 32), dim3(32, 8), 0, stream>>>(Wur, WrT, 2 * H, H);
  transpose_cast_kernel<<<dim3(H / 32, H / 32), dim3(32, 8), 0, stream>>>(U, UT, H, 0);

  // K1: G = prev@Wr -> reset -> X (bf16).  grid bx = n*32 + p
  gemm_panel<0><<<512, 512, 0, stream>>>(prevb, WrT, inp, nullptr, nullptr, Xb, nullptr);
  // K2: P = X@U -> out
  gemm_panel<1><<<512, 512, 0, stream>>>(Xb, UT, inp, prevb, mask, nullptr, out);
}